// Round 4
// baseline (2328.276 us; speedup 1.0000x reference)
//
#include <hip/hip_runtime.h>
#include <hip/hip_fp16.h>
#include <cstdint>
#include <cstddef>

#define BB 8
#define SS 2
#define TT 512
#define CC 2048
#define ND 1024
#define AD 16384
#define NN 256
#define AN 2048

// ---------------------------------------------------------------------------
// prep: per-graph counting sort of arcs by dst. Record packs indices into one
// u32: src | pdf<<10 | dst<<21 (src<1024, pdf<2048, dst<1024); payload .y is
// exp(weight). One block per graph, blockDim.x == N (power of 2).
// ---------------------------------------------------------------------------
__global__ void prep_kernel(const int* __restrict__ src, const int* __restrict__ dst,
                            const int* __restrict__ pdf, const float* __restrict__ w,
                            uint2* __restrict__ arcs, int N, int A)
{
    __shared__ int cnt[1024];
    __shared__ int pos[1024];
    const int g = blockIdx.x;
    src += (size_t)g * A; dst += (size_t)g * A; pdf += (size_t)g * A; w += (size_t)g * A;
    arcs += (size_t)g * A;
    const int tid = threadIdx.x;
    cnt[tid] = 0;
    __syncthreads();
    for (int a = tid; a < A; a += blockDim.x) atomicAdd(&cnt[dst[a]], 1);
    __syncthreads();
    const int deg = cnt[tid];
    pos[tid] = deg;
    __syncthreads();
    for (int off = 1; off < blockDim.x; off <<= 1) {
        int add = (tid >= off) ? pos[tid - off] : 0;
        __syncthreads();
        pos[tid] += add;
        __syncthreads();
    }
    const int excl = pos[tid] - deg;
    cnt[tid] = excl;
    __syncthreads();
    for (int a = tid; a < A; a += blockDim.x) {
        const int d2 = dst[a];
        const int p2 = atomicAdd(&cnt[d2], 1);
        arcs[p2] = make_uint2((unsigned)src[a] | ((unsigned)pdf[a] << 10) |
                              ((unsigned)d2 << 21),
                              __float_as_uint(__expf(w[a])));
    }
}

__device__ __forceinline__ unsigned pack_h2(float a, float b) {
    return (unsigned)__half_as_ushort(__float2half_rn(a)) |
           ((unsigned)__half_as_ushort(__float2half_rn(b)) << 16);
}
__device__ __forceinline__ float unpack_lo(unsigned u) {
    return __half2float(__ushort_as_half((unsigned short)(u & 0xffffu)));
}
__device__ __forceinline__ float unpack_hi(unsigned u) {
    return __half2float(__ushort_as_half((unsigned short)(u >> 16)));
}

// ---------------------------------------------------------------------------
// Linear-space FSM forward, 2 barriers/step, ping-pong beta buffers, renorm
// scale folded into the accumulation, elh time-paired in f16 (scaled by 4096;
// exact -L*12*ln2 correction at the end).
//   A(t):  nbeta_next[j] += inv_{t-1} * sum beta_raw[src]*e^w*elh_t[pdf]
//   C(t):  m_t = max_j nbeta_next[j] (shuffle + ds_max, consumed at A(t+1));
//          zero consumed buffer; (odd t) stage elh pair for t+2,t+3.
// ---------------------------------------------------------------------------
template<int APT, int NST>
__device__ void fsm_forward(const float* __restrict__ rowbase, int L,
    const uint2* __restrict__ arcs_g,
    const float* __restrict__ initv, const float* __restrict__ finalv,
    float* __restrict__ res,
    unsigned* elh2, float* buf0, float* buf1, unsigned* slot)
{
    const int tid = threadIdx.x;
    uint2 arc[APT];
    #pragma unroll
    for (int k = 0; k < APT; ++k) arc[k] = arcs_g[tid * APT + k];

    if (tid < NST) { buf0[tid] = __expf(initv[tid]); buf1[tid] = 0.f; }
    if (NST > 512) { buf0[tid + 512] = __expf(initv[tid + 512]); buf1[tid + 512] = 0.f; }
    // stage elh pair for steps 0,1
    {
        const float* r0 = rowbase;
        const float* r1 = rowbase + (size_t)(L > 1 ? 1 : 0) * CC;
        #pragma unroll
        for (int i = 0; i < 4; ++i) {
            const int p = tid + 512 * i;
            elh2[p] = pack_h2(4096.f * __expf(r0[p]), 4096.f * __expf(r1[p]));
        }
    }
    if (tid == 0) { slot[0] = __float_as_uint(1.0f); slot[1] = 0u; }
    float S = 0.f;
    __syncthreads();

    float bb[APT];
    unsigned ee[APT];
    float pf[8];

    for (int t2 = 0; t2 < L; t2 += 2) {
        // ================= even step t = t2: buf0 -> buf1 =================
        {
            const float m0 = __uint_as_float(slot[0]);
            const float inv = 1.0f / m0;
            S += __logf(m0);
            #pragma unroll
            for (int k = 0; k < APT; ++k) bb[k] = buf0[arc[k].x & 1023u];
            #pragma unroll
            for (int k = 0; k < APT; ++k) ee[k] = elh2[(arc[k].x >> 10) & 2047u];
            // prefetch llh rows t2+2, t2+3 (clamped; unused rows never consumed)
            {
                const int ra = (t2 + 2 < TT) ? t2 + 2 : TT - 1;
                const int rb = (t2 + 3 < TT) ? t2 + 3 : TT - 1;
                const float* pa = rowbase + (size_t)ra * CC;
                const float* pb = rowbase + (size_t)rb * CC;
                #pragma unroll
                for (int i = 0; i < 4; ++i) {
                    pf[i]     = pa[tid + 512 * i];
                    pf[4 + i] = pb[tid + 512 * i];
                }
            }
            float acc = 0.f;
            unsigned rd = arc[0].x >> 21;
            #pragma unroll
            for (int k = 0; k < APT; ++k) {
                acc += bb[k] * __uint_as_float(arc[k].y) * unpack_lo(ee[k]);
                const unsigned nd = (k + 1 < APT) ? (arc[k + 1].x >> 21) : 0xffffffffu;
                if (nd != rd) { atomicAdd(&buf1[rd], acc * inv); acc = 0.f; rd = nd; }
            }
        }
        __syncthreads();
        // C(even): max of buf1 -> slot[1]; zero buf0; reset slot[0]
        {
            float n0 = 0.f, n1 = 0.f;
            if (tid < NST) { n0 = buf1[tid]; buf0[tid] = 0.f; }
            if (NST > 512) { n1 = buf1[tid + 512]; buf0[tid + 512] = 0.f; }
            float wm = fmaxf(n0, n1);
            #pragma unroll
            for (int off = 32; off > 0; off >>= 1) wm = fmaxf(wm, __shfl_xor(wm, off));
            if ((tid & 63) == 0) atomicMax(&slot[1], __float_as_uint(wm));
            if (tid == 0) slot[0] = 0u;
        }
        __syncthreads();

        if (t2 + 1 >= L) break;
        // ================= odd step t = t2+1: buf1 -> buf0 ================
        {
            const float m1 = __uint_as_float(slot[1]);
            const float inv = 1.0f / m1;
            S += __logf(m1);
            #pragma unroll
            for (int k = 0; k < APT; ++k) bb[k] = buf1[arc[k].x & 1023u];
            float acc = 0.f;
            unsigned rd = arc[0].x >> 21;
            #pragma unroll
            for (int k = 0; k < APT; ++k) {
                acc += bb[k] * __uint_as_float(arc[k].y) * unpack_hi(ee[k]);
                const unsigned nd = (k + 1 < APT) ? (arc[k + 1].x >> 21) : 0xffffffffu;
                if (nd != rd) { atomicAdd(&buf0[rd], acc * inv); acc = 0.f; rd = nd; }
            }
        }
        __syncthreads();
        // C(odd): max of buf0 -> slot[0]; zero buf1; reset slot[1]; stage elh2
        {
            float n0 = 0.f, n1 = 0.f;
            if (tid < NST) { n0 = buf0[tid]; buf1[tid] = 0.f; }
            if (NST > 512) { n1 = buf0[tid + 512]; buf1[tid + 512] = 0.f; }
            float wm = fmaxf(n0, n1);
            #pragma unroll
            for (int off = 32; off > 0; off >>= 1) wm = fmaxf(wm, __shfl_xor(wm, off));
            if ((tid & 63) == 0) atomicMax(&slot[0], __float_as_uint(wm));
            if (tid == 0) slot[1] = 0u;
            if (t2 + 2 < L) {
                #pragma unroll
                for (int i = 0; i < 4; ++i) {
                    elh2[tid + 512 * i] = pack_h2(4096.f * __expf(pf[i]),
                                                  4096.f * __expf(pf[4 + i]));
                }
            }
        }
        __syncthreads();
    }

    // res = S + log( sum_j nbeta_final[j] * e^{final_j} ) - L*log(4096)
    const float* fb = (L & 1) ? buf1 : buf0;
    float v = 0.f;
    if (tid < NST) v += fb[tid] * __expf(finalv[tid]);
    if (NST > 512) v += fb[tid + 512] * __expf(finalv[tid + 512]);
    #pragma unroll
    for (int off = 32; off > 0; off >>= 1) v += __shfl_xor(v, off);
    __syncthreads();
    float* red = (float*)elh2;
    if ((tid & 63) == 0) red[tid >> 6] = v;
    __syncthreads();
    if (tid == 0) {
        float s2 = 0.f;
        for (int i = 0; i < 8; ++i) s2 += red[i];
        *res = S + __logf(s2) - (float)L * (12.0f * 0.6931471805599453f);
    }
}

__global__ __launch_bounds__(512, 2) void fwd_kernel(
    const float* __restrict__ est, const int* __restrict__ seqlen,
    const uint2* __restrict__ den_arcs,
    const float* __restrict__ den_init, const float* __restrict__ den_final,
    const uint2* __restrict__ num_arcs,
    const float* __restrict__ num_init, const float* __restrict__ num_final,
    float* __restrict__ res)
{
    __shared__ unsigned elh2[2048];
    __shared__ float buf0[1024];
    __shared__ float buf1[1024];
    __shared__ unsigned slot[2];
    const int bid = blockIdx.x;
    if (bid < 16) {
        const int s = bid >> 3, b = bid & 7;
        const float* rowbase = est + (size_t)(b * SS + s) * TT * CC;
        const int L = seqlen[b * SS + s];
        fsm_forward<32, ND>(rowbase, L, den_arcs, den_init, den_final,
                            &res[bid], elh2, buf0, buf1, slot);
    } else {
        const int q = bid - 16;
        const int p = q >> 4, g = q & 15;
        const int s = g >> 3, b = g & 7;
        const int sp = p ? (1 - s) : s;
        const float* rowbase = est + (size_t)(b * SS + sp) * TT * CC;
        const int L = seqlen[b * SS + sp];
        fsm_forward<4, NN>(rowbase, L,
                           num_arcs + (size_t)g * AN,
                           num_init + (size_t)g * NN, num_final + (size_t)g * NN,
                           &res[16 + p * 16 + g], elh2, buf0, buf1, slot);
    }
}

// res layout: [0..15] den (s*8+b), [16..31] num perm0, [32..47] num perm1
__global__ void finalize_kernel(const float* __restrict__ res, float* __restrict__ out)
{
    if (threadIdx.x == 0 && blockIdx.x == 0) {
        float loss = 0.f;
        for (int b = 0; b < BB; ++b) {
            const float den = res[b] + res[8 + b];
            const float n0  = res[16 + b] + res[16 + 8 + b];
            const float n1  = res[32 + b] + res[32 + 8 + b];
            const float nm  = fminf(n0, n1);
            loss += -(nm - den);
        }
        out[0] = loss;
    }
}

extern "C" void kernel_launch(void* const* d_in, const int* in_sizes, int n_in,
                              void* d_out, int out_size, void* d_ws, size_t ws_size,
                              hipStream_t stream)
{
    const float* est       = (const float*)d_in[0];
    const int*   seqlen    = (const int*)  d_in[1];
    const int*   den_src   = (const int*)  d_in[2];
    const int*   den_dst   = (const int*)  d_in[3];
    const int*   den_pdf   = (const int*)  d_in[4];
    const float* den_w     = (const float*)d_in[5];
    const float* den_init  = (const float*)d_in[6];
    const float* den_final = (const float*)d_in[7];
    const int*   num_src   = (const int*)  d_in[8];
    const int*   num_dst   = (const int*)  d_in[9];
    const int*   num_pdf   = (const int*)  d_in[10];
    const float* num_w     = (const float*)d_in[11];
    const float* num_init  = (const float*)d_in[12];
    const float* num_final = (const float*)d_in[13];

    char* ws = (char*)d_ws;
    uint2* den_arcs = (uint2*)(ws + 0);        // 131072 B
    uint2* num_arcs = (uint2*)(ws + 131072);   // 262144 B -> end 393216
    float* res      = (float*)(ws + 393216);   // 192 B

    prep_kernel<<<1, 1024, 0, stream>>>(den_src, den_dst, den_pdf, den_w,
                                        den_arcs, ND, AD);
    prep_kernel<<<16, 256, 0, stream>>>(num_src, num_dst, num_pdf, num_w,
                                        num_arcs, NN, AN);

    fwd_kernel<<<48, 512, 0, stream>>>(est, seqlen,
                                       den_arcs, den_init, den_final,
                                       num_arcs, num_init, num_final, res);

    finalize_kernel<<<1, 64, 0, stream>>>(res, (float*)d_out);
}

// Round 5
// 2176.676 us; speedup vs baseline: 1.0696x; 1.0696x over previous
//
#include <hip/hip_runtime.h>
#include <cstdint>
#include <cstddef>

#define BB 8
#define SS 2
#define TT 512
#define CC 2048
#define ND 1024
#define AD 16384
#define NN 256
#define AN 2048

// ---------------------------------------------------------------------------
// prep: per-graph counting sort of arcs by dst. Record packs indices into one
// u32: src | pdf<<10 | dst<<21 (src<1024, pdf<2048, dst<1024); payload .y is
// exp(weight). One block per graph, blockDim.x == N (power of 2).
// ---------------------------------------------------------------------------
__global__ void prep_kernel(const int* __restrict__ src, const int* __restrict__ dst,
                            const int* __restrict__ pdf, const float* __restrict__ w,
                            uint2* __restrict__ arcs, int N, int A)
{
    __shared__ int cnt[1024];
    __shared__ int pos[1024];
    const int g = blockIdx.x;
    src += (size_t)g * A; dst += (size_t)g * A; pdf += (size_t)g * A; w += (size_t)g * A;
    arcs += (size_t)g * A;
    const int tid = threadIdx.x;
    cnt[tid] = 0;
    __syncthreads();
    for (int a = tid; a < A; a += blockDim.x) atomicAdd(&cnt[dst[a]], 1);
    __syncthreads();
    const int deg = cnt[tid];
    pos[tid] = deg;
    __syncthreads();
    for (int off = 1; off < blockDim.x; off <<= 1) {
        int add = (tid >= off) ? pos[tid - off] : 0;
        __syncthreads();
        pos[tid] += add;
        __syncthreads();
    }
    const int excl = pos[tid] - deg;
    cnt[tid] = excl;
    __syncthreads();
    for (int a = tid; a < A; a += blockDim.x) {
        const int d2 = dst[a];
        const int p2 = atomicAdd(&cnt[d2], 1);
        arcs[p2] = make_uint2((unsigned)src[a] | ((unsigned)pdf[a] << 10) |
                              ((unsigned)d2 << 21),
                              __float_as_uint(__expf(w[a])));
    }
}

// ---------------------------------------------------------------------------
// Linear-space FSM forward, sum-renormalization with 2-step lag.
//   A(t): b(t)[j] = inv(t) * sum_{dst=j} b(t-1)[src]*e^w*elh_t[pdf]
//         psum[tid] = thread's raw total;  wave 7 (t>=1) finishes the
//         reduction of psum(t-1) -> P(t-1) = inv(t-1)*T; S += log P;
//         inv(t+1) = 1/P(t-1) -> islot[(t+1)&1].
//   C(t): owners zero the read buffer; threads 0..127 column-sum psum
//         (b128) into red[128]; stage elh row t+1.
// Exact: every folded 1/P(k) has log P(k) in S; extra log P(L-2) subtracted
// at the end. alpha == S + log(b) identically (pure algebra, no clamps bind:
// max term of each segment-logsumexp always contributes, NEG/1e-30 inactive).
// TPB = 512; A = 512*APT exactly; arcs dst-sorted, APT per thread in regs.
// ---------------------------------------------------------------------------
template<int APT, int NST>
__device__ void fsm_forward(const float* __restrict__ rowbase, int L,
    const uint2* __restrict__ arcs_g,
    const float* __restrict__ initv, const float* __restrict__ finalv,
    float* __restrict__ res,
    float* elh, float* buf0, float* buf1, float* psum, float* red,
    unsigned* islot, float* sS)
{
    const int tid = threadIdx.x;
    uint2 arc[APT];
    #pragma unroll
    for (int k = 0; k < APT; ++k) arc[k] = arcs_g[tid * APT + k];

    if (tid < NST) { buf0[tid] = __expf(initv[tid]); buf1[tid] = 0.f; }
    if (NST > 512) { buf0[tid + 512] = __expf(initv[tid + 512]); buf1[tid + 512] = 0.f; }
    #pragma unroll
    for (int i = 0; i < 4; ++i) elh[tid + 512 * i] = __expf(rowbase[tid + 512 * i]);
    if (tid == 0) { islot[0] = __float_as_uint(1.0f); islot[1] = __float_as_uint(1.0f); }
    float inv_prev = 1.f, inv_cur = 1.f, Sacc = 0.f, lastP = 1.f;
    __syncthreads();

    for (int t = 0; t < L; ++t) {
        float* bufR = (t & 1) ? buf1 : buf0;
        float* bufW = (t & 1) ? buf0 : buf1;
        const float inv = __uint_as_float(islot[t & 1]);
        // prefetch next llh row (global, hidden under gathers)
        float pf[4];
        {
            const int rn = (t + 1 < L) ? t + 1 : t;
            const float* nb = rowbase + (size_t)rn * CC;
            #pragma unroll
            for (int i = 0; i < 4; ++i) pf[i] = nb[tid + 512 * i];
        }
        // batched gathers (independent -> stay in flight)
        float bb[APT], ef[APT];
        #pragma unroll
        for (int k = 0; k < APT; ++k) bb[k] = bufR[arc[k].x & 1023u];
        #pragma unroll
        for (int k = 0; k < APT; ++k) ef[k] = elh[(arc[k].x >> 10) & 2047u];
        float tot = 0.f, acc = 0.f;
        #pragma unroll
        for (int k = 0; k < APT; ++k) {
            const float p = bb[k] * __uint_as_float(arc[k].y) * ef[k];
            acc += p; tot += p;
            const unsigned nd = (k + 1 < APT) ? (arc[k + 1].x >> 21) : 0xffffffffu;
            if (nd != (arc[k].x >> 21)) {
                atomicAdd(&bufW[arc[k].x >> 21], acc * inv);
                acc = 0.f;
            }
        }
        psum[tid] = tot;
        // wave 7: finish reduction of psum(t-1) (overlapped with other waves)
        if (t && (tid >> 6) == 7) {
            const int l = tid & 63;
            float r = red[l] + red[l + 64];
            #pragma unroll
            for (int off = 32; off > 0; off >>= 1) r += __shfl_xor(r, off);
            const float P = inv_prev * r;      // P(t-1), all lanes identical
            Sacc += __logf(P);
            lastP = P;
            const float newInv = 1.0f / P;     // inv(t+1)
            inv_prev = inv_cur; inv_cur = newInv;
            if (l == 0) islot[(t + 1) & 1] = __float_as_uint(newInv);
        }
        __syncthreads();
        // ---- C phase
        if (tid < NST) bufR[tid] = 0.f;
        if (NST > 512) bufR[tid + 512] = 0.f;
        if (tid < 128) {
            const float4 q = *(const float4*)&psum[tid * 4];
            red[tid] = q.x + q.y + q.z + q.w;
        }
        if (t + 1 < L) {
            #pragma unroll
            for (int i = 0; i < 4; ++i) elh[tid + 512 * i] = __expf(pf[i]);
        }
        __syncthreads();
    }

    // final: res = S + log( sum_j b(L-1)[j] * e^{final_j} )
    const float* fb = (L & 1) ? buf1 : buf0;
    float v = 0.f;
    if (tid < NST) v = fb[tid] * __expf(finalv[tid]);
    if (NST > 512) v += fb[tid + 512] * __expf(finalv[tid + 512]);
    psum[tid] = v;
    if (tid == 448) sS[0] = Sacc - __logf(lastP);
    __syncthreads();
    if (tid < 128) {
        const float4 q = *(const float4*)&psum[tid * 4];
        red[tid] = q.x + q.y + q.z + q.w;
    }
    __syncthreads();
    if (tid < 32) {
        const float4 q = *(const float4*)&red[tid * 4];
        psum[tid] = q.x + q.y + q.z + q.w;
    }
    __syncthreads();
    if (tid == 0) {
        float s2 = 0.f;
        for (int i = 0; i < 32; ++i) s2 += psum[i];
        *res = sS[0] + __logf(s2);
    }
}

__global__ __launch_bounds__(512) void fwd_kernel(
    const float* __restrict__ est, const int* __restrict__ seqlen,
    const uint2* __restrict__ den_arcs,
    const float* __restrict__ den_init, const float* __restrict__ den_final,
    const uint2* __restrict__ num_arcs,
    const float* __restrict__ num_init, const float* __restrict__ num_final,
    float* __restrict__ res)
{
    __shared__ float elh[2048];
    __shared__ float buf0[1024];
    __shared__ float buf1[1024];
    __shared__ float psum[512];
    __shared__ float red[128];
    __shared__ unsigned islot[2];
    __shared__ float sS[1];
    const int bid = blockIdx.x;
    if (bid < 16) {
        const int s = bid >> 3, b = bid & 7;
        const float* rowbase = est + (size_t)(b * SS + s) * TT * CC;
        const int L = seqlen[b * SS + s];
        fsm_forward<32, ND>(rowbase, L, den_arcs, den_init, den_final,
                            &res[bid], elh, buf0, buf1, psum, red, islot, sS);
    } else {
        const int q = bid - 16;
        const int p = q >> 4, g = q & 15;
        const int s = g >> 3, b = g & 7;
        const int sp = p ? (1 - s) : s;
        const float* rowbase = est + (size_t)(b * SS + sp) * TT * CC;
        const int L = seqlen[b * SS + sp];
        fsm_forward<4, NN>(rowbase, L,
                           num_arcs + (size_t)g * AN,
                           num_init + (size_t)g * NN, num_final + (size_t)g * NN,
                           &res[16 + p * 16 + g], elh, buf0, buf1, psum, red, islot, sS);
    }
}

// res layout: [0..15] den (s*8+b), [16..31] num perm0, [32..47] num perm1
__global__ void finalize_kernel(const float* __restrict__ res, float* __restrict__ out)
{
    if (threadIdx.x == 0 && blockIdx.x == 0) {
        float loss = 0.f;
        for (int b = 0; b < BB; ++b) {
            const float den = res[b] + res[8 + b];
            const float n0  = res[16 + b] + res[16 + 8 + b];
            const float n1  = res[32 + b] + res[32 + 8 + b];
            const float nm  = fminf(n0, n1);
            loss += -(nm - den);
        }
        out[0] = loss;
    }
}

extern "C" void kernel_launch(void* const* d_in, const int* in_sizes, int n_in,
                              void* d_out, int out_size, void* d_ws, size_t ws_size,
                              hipStream_t stream)
{
    const float* est       = (const float*)d_in[0];
    const int*   seqlen    = (const int*)  d_in[1];
    const int*   den_src   = (const int*)  d_in[2];
    const int*   den_dst   = (const int*)  d_in[3];
    const int*   den_pdf   = (const int*)  d_in[4];
    const float* den_w     = (const float*)d_in[5];
    const float* den_init  = (const float*)d_in[6];
    const float* den_final = (const float*)d_in[7];
    const int*   num_src   = (const int*)  d_in[8];
    const int*   num_dst   = (const int*)  d_in[9];
    const int*   num_pdf   = (const int*)  d_in[10];
    const float* num_w     = (const float*)d_in[11];
    const float* num_init  = (const float*)d_in[12];
    const float* num_final = (const float*)d_in[13];

    char* ws = (char*)d_ws;
    uint2* den_arcs = (uint2*)(ws + 0);        // 131072 B
    uint2* num_arcs = (uint2*)(ws + 131072);   // 262144 B -> end 393216
    float* res      = (float*)(ws + 393216);   // 192 B

    prep_kernel<<<1, 1024, 0, stream>>>(den_src, den_dst, den_pdf, den_w,
                                        den_arcs, ND, AD);
    prep_kernel<<<16, 256, 0, stream>>>(num_src, num_dst, num_pdf, num_w,
                                        num_arcs, NN, AN);

    fwd_kernel<<<48, 512, 0, stream>>>(est, seqlen,
                                       den_arcs, den_init, den_final,
                                       num_arcs, num_init, num_final, res);

    finalize_kernel<<<1, 64, 0, stream>>>(res, (float*)d_out);
}